// Round 16
// baseline (186.831 us; speedup 1.0000x reference)
//
#include <hip/hip_runtime.h>

// Fused MHA block: out = LayerNorm(x + MHA(x)).  B=4, S=2048, D=1024, H=16, dk=64.
// bf16 MFMA internal, fp32 I/O.
//
// Round 16 = Round 14 (185.8us best) + attn counted-vmcnt triple-buffer:
//  R15 (KVBLK=128) reverted. The lever is the vmcnt(0) drain inside each
//  __syncthreads, not barrier count. New attn staging: 3 bufs (K 3x[64][64],
//  V 3x[64][64], 48KB), depth-2 prefetch, per tile: s_waitcnt vmcnt(2) (tail 0)
//  -> raw s_barrier -> stage t+2 into buf freed by barrier -> compute buf t%3.
//  Wait BEFORE barrier makes per-wave load completion collective (R13-proven).
//  GEMMs (counted-vmcnt 128x128), cvt, LN, dot2 l-sum unchanged.

#define SEQ 2048
#define DMODEL 1024
#define NH 16
#define DK 64
#define NROWS 8192  // B*S

typedef unsigned short u16;
typedef unsigned int u32;
typedef __bf16 bf16;
typedef bf16 bf16x2 __attribute__((ext_vector_type(2)));
typedef bf16 bf16x8 __attribute__((ext_vector_type(8)));
typedef float f32x4 __attribute__((ext_vector_type(4)));
typedef float f32x16 __attribute__((ext_vector_type(16)));
typedef unsigned u32x2 __attribute__((ext_vector_type(2)));

__device__ inline u16 bfbits(float f) { return __builtin_bit_cast(u16, (bf16)f); }
__device__ inline u32 packbf2(float a, float b) {
    return (u32)bfbits(a) | ((u32)bfbits(b) << 16);
}

// Schraudolph exp2 (validated R8+): full-rate VALU, error cancels in norm.
__device__ inline float sexp2(float s) {
    return __builtin_bit_cast(float, (u32)(int)fmaf(s, 8388608.0f, 1064986823.0f));
}

// async global->LDS, 16B per lane; LDS dest = wave-uniform base + lane*16
__device__ inline void gload16(const u16* g, u16* l) {
    __builtin_amdgcn_global_load_lds(
        (const __attribute__((address_space(1))) u32*)g,
        (__attribute__((address_space(3))) u32*)l, 16, 0, 0);
}

// cross-half exchange (validated rounds 2-15)
__device__ inline void plswap(u32& a, u32& b) {
#if __has_builtin(__builtin_amdgcn_permlane32_swap)
    u32x2 r = __builtin_amdgcn_permlane32_swap(a, b, false, false);
    a = r[0]; b = r[1];
#else
    u32 xa = __shfl_xor(a, 32), xb = __shfl_xor(b, 32);
    int hi = (threadIdx.x & 63) >> 5;
    u32 na = hi ? xb : a;
    u32 nb = hi ? b : xa;
    a = na; b = nb;
#endif
}

// ---------------- fused fp32 -> bf16 convert: x + 4 weights ----------------
__global__ __launch_bounds__(256) void cvt_all(
    const float* __restrict__ x,  const float* __restrict__ w0,
    const float* __restrict__ w1, const float* __restrict__ w2,
    const float* __restrict__ w3,
    u16* __restrict__ xo, u16* __restrict__ o0, u16* __restrict__ o1,
    u16* __restrict__ o2, u16* __restrict__ o3) {
    const int b = blockIdx.x;
    const float* in;
    u16* out;
    int base;
    if (b < 8192) {
        in = x; out = xo; base = b << 10;
    } else {
        const int wsel = (b - 8192) >> 10;
        base = ((b - 8192) & 1023) << 10;
        switch (wsel) {
            case 0: in = w0; out = o0; break;
            case 1: in = w1; out = o1; break;
            case 2: in = w2; out = o2; break;
            default: in = w3; out = o3; break;
        }
    }
    const int i = base + threadIdx.x * 4;
    float4 v = *(const float4*)(in + i);
    ushort4 o;
    o.x = bfbits(v.x); o.y = bfbits(v.y); o.z = bfbits(v.z); o.w = bfbits(v.w);
    *(ushort4*)(out + i) = o;
}

// ---------------- unified counted-vmcnt GEMM (R13, unchanged) ----------------
template <int EPI>
__global__ __launch_bounds__(512) void gemm_piped(
    const u16* __restrict__ A, const u16* __restrict__ Bm,
    const float* __restrict__ bias0, const float* __restrict__ bias1,
    const float* __restrict__ bias2,
    u16* __restrict__ Qo, u16* __restrict__ Ko, u16* __restrict__ Vo,
    const float* __restrict__ xres, float* __restrict__ yout) {
    __shared__ __align__(16) u16 smem[32768];   // As[2]@0, Bs[2]@16384 (elems)

    const int tid  = threadIdx.x;
    const int lane = tid & 63;
    const int w    = tid >> 6;
    const int wr   = (w >> 1) * 32;
    const int wc   = (w & 1) * 64;
    const int l16  = lane & 15;
    const int lq   = lane >> 4;
    const int m0   = blockIdx.x * 128;
    const int n0   = blockIdx.y * 128;

    f32x4 acc[2][4];
#pragma unroll
    for (int m = 0; m < 2; m++)
#pragma unroll
        for (int n = 0; n < 4; n++) {
            f32x4 z = {0.f, 0.f, 0.f, 0.f};
            acc[m][n] = z;
        }

    const int l8r = lane >> 3;
    const int sch = (lane & 7) ^ l8r;
    const u16* a_g = A  + (size_t)(m0 + w * 8 + l8r) * 1024 + sch * 8;
    const u16* b_g = Bm + (size_t)(n0 + w * 8 + l8r) * 1024 + sch * 8;
    u16* asd = smem + w * 512;
    u16* bsd = smem + 16384 + w * 512;

#define STAGE(kt, c) do {                                              \
        gload16(a_g + (kt) * 64,         asd + (c) * 8192);            \
        gload16(a_g + 65536 + (kt) * 64, asd + (c) * 8192 + 4096);     \
        gload16(b_g + (kt) * 64,         bsd + (c) * 8192);            \
        gload16(b_g + 65536 + (kt) * 64, bsd + (c) * 8192 + 4096);     \
    } while (0)

    STAGE(0, 0);
    STAGE(1, 1);

    for (int kt = 0; kt < 16; kt++) {
        const int cur = kt & 1;
        if (kt < 15) asm volatile("s_waitcnt vmcnt(4)" ::: "memory");
        else         asm volatile("s_waitcnt vmcnt(0)" ::: "memory");
        __builtin_amdgcn_s_barrier();

        const u16* Asl = smem + cur * 8192;
        const u16* Bsl = smem + 16384 + cur * 8192;
#pragma unroll
        for (int kk = 0; kk < 2; kk++) {
            bf16x8 af[2], bfr[4];
#pragma unroll
            for (int m = 0; m < 2; m++)
                af[m] = *(const bf16x8*)&Asl[(wr + m * 16 + l16) * 64 +
                                             (((kk << 2) | lq) ^ (l16 & 7)) * 8];
#pragma unroll
            for (int n = 0; n < 4; n++)
                bfr[n] = *(const bf16x8*)&Bsl[(wc + n * 16 + l16) * 64 +
                                              (((kk << 2) | lq) ^ (l16 & 7)) * 8];
            __builtin_amdgcn_s_setprio(1);
#pragma unroll
            for (int m = 0; m < 2; m++)
#pragma unroll
                for (int n = 0; n < 4; n++)
                    acc[m][n] = __builtin_amdgcn_mfma_f32_16x16x32_bf16(
                        af[m], bfr[n], acc[m][n], 0, 0, 0);
            __builtin_amdgcn_s_setprio(0);
        }
        __builtin_amdgcn_s_barrier();
        if (kt < 14) STAGE(kt + 2, cur);
    }
#undef STAGE

    if (EPI == 0 && n0 >= 2048) {
        const int e0 = n0 - 2048;
#pragma unroll
        for (int m = 0; m < 2; m++)
#pragma unroll
            for (int n = 0; n < 4; n++) {
                const int col = wc + n * 16 + l16;
                const int row = wr + lq * 4 + m * 16;
                const float bias = bias2[e0 + col];
                ushort4 pk;
                pk.x = bfbits(acc[m][n][0] + bias);
                pk.y = bfbits(acc[m][n][1] + bias);
                pk.z = bfbits(acc[m][n][2] + bias);
                pk.w = bfbits(acc[m][n][3] + bias);
                *(ushort4*)&smem[col * 128 + (row ^ ((col & 7) << 3))] = pk;
            }
        __syncthreads();
        const int b = m0 >> 11;
        const int sbase = m0 & 2047;
#pragma unroll
        for (int i = 0; i < 4; i++) {
            const int c = tid + 512 * i;
            const int col = c >> 4;
            const int s0 = (c & 15) * 8;
            uint4 val = *(const uint4*)&smem[col * 128 + (s0 ^ ((col & 7) << 3))];
            const int eg = e0 + col;
            const int bh = b * NH + (eg >> 6);
            *(uint4*)&Vo[((size_t)bh * DK + (eg & 63)) * SEQ + sbase + s0] = val;
        }
        return;
    }

    const int rbase = m0 + wr + lq * 4;
#pragma unroll
    for (int m = 0; m < 2; m++)
#pragma unroll
        for (int n = 0; n < 4; n++) {
            if (EPI == 0) {
                const int which = n0 >> 10;
                const int e = (n0 & 1023) + wc + n * 16 + l16;
                const float bias = (which == 0) ? bias0[e] : bias1[e];
                const int h = e >> 6, d = e & 63;
#pragma unroll
                for (int r = 0; r < 4; r++) {
                    const int row = rbase + m * 16 + r;
                    float v = acc[m][n][r] + bias;
                    if (which == 0) v *= 0.18033688011112042f;
                    const int b = row >> 11, s = row & 2047;
                    const int bh = b * NH + h;
                    if (which == 0)
                        Qo[((size_t)bh * SEQ + s) * DK + d] = bfbits(v);
                    else
                        Ko[((size_t)bh * SEQ + s) * DK + d] = bfbits(v);
                }
            } else {
                const int col = n0 + wc + n * 16 + l16;
#pragma unroll
                for (int r = 0; r < 4; r++) {
                    const int row = rbase + m * 16 + r;
                    float v = acc[m][n][r] + bias0[col] + xres[(size_t)row * DMODEL + col];
                    yout[(size_t)row * DMODEL + col] = v;
                }
            }
        }
}

// ---------------- flash attention: R14 body + counted-vmcnt triple-buffer ----------------
// grid (B*H, S/256), 512 thr = 8 waves; wave w owns q rows [q0, q0+32).
// LDS 48KB: K[3][64][64] @0, V^T[3][64][64] @12288 (elem offsets, 4096/buf).
// Per tile: s_waitcnt vmcnt(2) [tail 0] -> s_barrier -> stage t+2 -> compute.
__global__ __launch_bounds__(512) void attn(const u16* __restrict__ Qb,
                                            const u16* __restrict__ Kb,
                                            const u16* __restrict__ Vtb,
                                            u16* __restrict__ ctx) {
    __shared__ __align__(16) u16 smem[24576];

    const int tid  = threadIdx.x;
    const int lane = tid & 63;
    const int w    = tid >> 6;
    const int q    = lane & 31;
    const int hi   = lane >> 5;
    const int bh   = blockIdx.x;
    const int q0   = blockIdx.y * 256 + w * 32;

    const u16* qp = Qb + ((size_t)bh * SEQ + q0 + q) * DK + hi * 8;
    bf16x8 qf0 = *(const bf16x8*)(qp);
    bf16x8 qf1 = *(const bf16x8*)(qp + 16);
    bf16x8 qf2 = *(const bf16x8*)(qp + 32);
    bf16x8 qf3 = *(const bf16x8*)(qp + 48);

    // staging: wave w stages K rows [w*8, w*8+8) and V^T rows [w*8, w*8+8);
    // one gload16 each per tile. lane: row-in-8 = l>>3, chunk = (l&7)^(l>>3).
    const int l8r = lane >> 3;
    const int sch = (lane & 7) ^ l8r;
    const u16* kg = Kb  + ((size_t)bh * SEQ + w * 8 + l8r) * 64 + sch * 8;   // +4096/tile
    const u16* vg = Vtb + ((size_t)bh * DK  + w * 8 + l8r) * SEQ + sch * 8;  // +64/tile
    u16* kld = smem + w * 512;            // + buf*4096
    u16* vld = smem + 12288 + w * 512;    // + buf*4096

    f32x16 oacc0, oacc1;
#pragma unroll
    for (int r = 0; r < 16; r++) { oacc0[r] = 0.f; oacc1[r] = 0.f; }
    f32x16 fzero;
#pragma unroll
    for (int r = 0; r < 16; r++) fzero[r] = 0.f;
    float la = 0.f, lb = 0.f;

#if __has_builtin(__builtin_amdgcn_fdot2_f32_bf16)
    bf16x2 ones2;
    ones2[0] = (bf16)1.0f; ones2[1] = (bf16)1.0f;
#endif

#define ASTAGE(t, b) do {                                   \
        gload16(kg + (size_t)(t) * 4096, kld + (b) * 4096); \
        gload16(vg + (size_t)(t) * 64,   vld + (b) * 4096); \
    } while (0)

    // prologue: depth-2 prefetch
    ASTAGE(0, 0);
    ASTAGE(1, 1);

    int cur = 0;     // buffer holding tile t
    int nx2 = 2;     // buffer for tile t+2 (== buffer freed by this iter's barrier)
    for (int t = 0; t < SEQ / 64; t++) {
        // counted wait BEFORE barrier: each wave drains its own tile-t loads
        // (leaving t+1's 2 in flight); barrier then makes completion collective.
        if (t < SEQ / 64 - 1) asm volatile("s_waitcnt vmcnt(2)" ::: "memory");
        else                  asm volatile("s_waitcnt vmcnt(0)" ::: "memory");
        __builtin_amdgcn_s_barrier();
        if (t < SEQ / 64 - 2) ASTAGE(t + 2, nx2);

        const u16* Kl = smem + cur * 4096;
        const u16* Vl = smem + 12288 + cur * 4096;

        f32x16 sacc0, sacc1;
        {
            bf16x8 k00 = *(const bf16x8*)&Kl[(q)      * 64 + ((0 | hi) ^ (q & 7)) * 8];
            bf16x8 k01 = *(const bf16x8*)&Kl[(q)      * 64 + ((2 | hi) ^ (q & 7)) * 8];
            bf16x8 k02 = *(const bf16x8*)&Kl[(q)      * 64 + ((4 | hi) ^ (q & 7)) * 8];
            bf16x8 k03 = *(const bf16x8*)&Kl[(q)      * 64 + ((6 | hi) ^ (q & 7)) * 8];
            bf16x8 k10 = *(const bf16x8*)&Kl[(q + 32) * 64 + ((0 | hi) ^ (q & 7)) * 8];
            bf16x8 k11 = *(const bf16x8*)&Kl[(q + 32) * 64 + ((2 | hi) ^ (q & 7)) * 8];
            bf16x8 k12 = *(const bf16x8*)&Kl[(q + 32) * 64 + ((4 | hi) ^ (q & 7)) * 8];
            bf16x8 k13 = *(const bf16x8*)&Kl[(q + 32) * 64 + ((6 | hi) ^ (q & 7)) * 8];
            __builtin_amdgcn_s_setprio(1);
            sacc0 = __builtin_amdgcn_mfma_f32_32x32x16_bf16(k00, qf0, fzero, 0, 0, 0);
            sacc1 = __builtin_amdgcn_mfma_f32_32x32x16_bf16(k10, qf0, fzero, 0, 0, 0);
            sacc0 = __builtin_amdgcn_mfma_f32_32x32x16_bf16(k01, qf1, sacc0, 0, 0, 0);
            sacc1 = __builtin_amdgcn_mfma_f32_32x32x16_bf16(k11, qf1, sacc1, 0, 0, 0);
            sacc0 = __builtin_amdgcn_mfma_f32_32x32x16_bf16(k02, qf2, sacc0, 0, 0, 0);
            sacc1 = __builtin_amdgcn_mfma_f32_32x32x16_bf16(k12, qf2, sacc1, 0, 0, 0);
            sacc0 = __builtin_amdgcn_mfma_f32_32x32x16_bf16(k03, qf3, sacc0, 0, 0, 0);
            sacc1 = __builtin_amdgcn_mfma_f32_32x32x16_bf16(k13, qf3, sacc1, 0, 0, 0);
            __builtin_amdgcn_s_setprio(0);
        }

#pragma unroll
        for (int r = 0; r < 16; r++) sacc0[r] = sexp2(sacc0[r]);
#pragma unroll
        for (int r = 0; r < 16; r++) sacc1[r] = sexp2(sacc1[r]);

        u32 wa[8], wb[8];
#pragma unroll
        for (int i = 0; i < 8; i++) wa[i] = packbf2(sacc0[2 * i], sacc0[2 * i + 1]);
#pragma unroll
        for (int i = 0; i < 8; i++) wb[i] = packbf2(sacc1[2 * i], sacc1[2 * i + 1]);

#if __has_builtin(__builtin_amdgcn_fdot2_f32_bf16)
#pragma unroll
        for (int i = 0; i < 8; i++)
            la = __builtin_amdgcn_fdot2_f32_bf16(
                __builtin_bit_cast(bf16x2, wa[i]), ones2, la, false);
#pragma unroll
        for (int i = 0; i < 8; i++)
            lb = __builtin_amdgcn_fdot2_f32_bf16(
                __builtin_bit_cast(bf16x2, wb[i]), ones2, lb, false);
#else
        {
            float s0 = ((sacc0[0] + sacc0[1]) + (sacc0[2] + sacc0[3])) +
                       ((sacc0[4] + sacc0[5]) + (sacc0[6] + sacc0[7]));
            float s1 = ((sacc0[8] + sacc0[9]) + (sacc0[10] + sacc0[11])) +
                       ((sacc0[12] + sacc0[13]) + (sacc0[14] + sacc0[15]));
            float s2 = ((sacc1[0] + sacc1[1]) + (sacc1[2] + sacc1[3])) +
                       ((sacc1[4] + sacc1[5]) + (sacc1[6] + sacc1[7]));
            float s3 = ((sacc1[8] + sacc1[9]) + (sacc1[10] + sacc1[11])) +
                       ((sacc1[12] + sacc1[13]) + (sacc1[14] + sacc1[15]));
            la += (s0 + s1);
            lb += (s2 + s3);
        }
#endif

        plswap(wa[0], wa[2]); plswap(wa[1], wa[3]);
        plswap(wa[4], wa[6]); plswap(wa[5], wa[7]);
        plswap(wb[0], wb[2]); plswap(wb[1], wb[3]);
        plswap(wb[4], wb[6]); plswap(wb[5], wb[7]);
        union { u32 u[4]; bf16x8 v; } pf0, pf1, pf2, pf3;
        pf0.u[0] = wa[0]; pf0.u[1] = wa[1]; pf0.u[2] = wa[2]; pf0.u[3] = wa[3];
        pf1.u[0] = wa[4]; pf1.u[1] = wa[5]; pf1.u[2] = wa[6]; pf1.u[3] = wa[7];
        pf2.u[0] = wb[0]; pf2.u[1] = wb[1]; pf2.u[2] = wb[2]; pf2.u[3] = wb[3];
        pf3.u[0] = wb[4]; pf3.u[1] = wb[5]; pf3.u[2] = wb[6]; pf3.u[3] = wb[7];

        {
            bf16x8 v00 = *(const bf16x8*)&Vl[(q)      * 64 + ((0 | hi) ^ (q & 7)) * 8];
            bf16x8 v01 = *(const bf16x8*)&Vl[(q)      * 64 + ((2 | hi) ^ (q & 7)) * 8];
            bf16x8 v02 = *(const bf16x8*)&Vl[(q)      * 64 + ((4 | hi) ^ (q & 7)) * 8];
            bf16x8 v03 = *(const bf16x8*)&Vl[(q)      * 64 + ((6 | hi) ^ (q & 7)) * 8];
            bf16x8 v10 = *(const bf16x8*)&Vl[(q + 32) * 64 + ((0 | hi) ^ (q & 7)) * 8];
            bf16x8 v11 = *(const bf16x8*)&Vl[(q + 32) * 64 + ((2 | hi) ^ (q & 7)) * 8];
            bf16x8 v12 = *(const bf16x8*)&Vl[(q + 32) * 64 + ((4 | hi) ^ (q & 7)) * 8];
            bf16x8 v13 = *(const bf16x8*)&Vl[(q + 32) * 64 + ((6 | hi) ^ (q & 7)) * 8];
            __builtin_amdgcn_s_setprio(1);
            oacc0 = __builtin_amdgcn_mfma_f32_32x32x16_bf16(v00, pf0.v, oacc0, 0, 0, 0);
            oacc1 = __builtin_amdgcn_mfma_f32_32x32x16_bf16(v10, pf0.v, oacc1, 0, 0, 0);
            oacc0 = __builtin_amdgcn_mfma_f32_32x32x16_bf16(v01, pf1.v, oacc0, 0, 0, 0);
            oacc1 = __builtin_amdgcn_mfma_f32_32x32x16_bf16(v11, pf1.v, oacc1, 0, 0, 0);
            oacc0 = __builtin_amdgcn_mfma_f32_32x32x16_bf16(v02, pf2.v, oacc0, 0, 0, 0);
            oacc1 = __builtin_amdgcn_mfma_f32_32x32x16_bf16(v12, pf2.v, oacc1, 0, 0, 0);
            oacc0 = __builtin_amdgcn_mfma_f32_32x32x16_bf16(v03, pf3.v, oacc0, 0, 0, 0);
            oacc1 = __builtin_amdgcn_mfma_f32_32x32x16_bf16(v13, pf3.v, oacc1, 0, 0, 0);
            __builtin_amdgcn_s_setprio(0);
        }

        cur = (cur == 2) ? 0 : cur + 1;
        nx2 = (nx2 == 2) ? 0 : nx2 + 1;
    }
#undef ASTAGE

    __syncthreads();   // all waves done reading buffers before bounce overwrite

    float l_ = la + lb;
    const float lfull = l_ + __shfl_xor(l_, 32);
    const float invl = 1.f / lfull;
    const int wbase = w * 2048;
#pragma unroll
    for (int r = 0; r < 16; r++) {
        const int dk0 = (r & 3) + 8 * (r >> 2) + 4 * hi;
        const int dk1 = 32 + dk0;
        smem[wbase + q * 64 + (((dk0 >> 3) ^ (q & 7)) << 3) + (dk0 & 7)] = bfbits(oacc0[r] * invl);
        smem[wbase + q * 64 + (((dk1 >> 3) ^ (q & 7)) << 3) + (dk1 & 7)] = bfbits(oacc1[r] * invl);
    }
    __syncthreads();
    const int b = bh >> 4, h = bh & 15;
    const int r4 = lane >> 1;
    const int cc = (lane & 1) * 4;
#pragma unroll
    for (int c = 0; c < 4; c++) {
        const int chunk = cc + c;
        uint4 val = *(const uint4*)&smem[wbase + r4 * 64 + ((chunk ^ (r4 & 7)) << 3)];
        *(uint4*)&ctx[((size_t)(b * SEQ + q0 + r4)) * DMODEL + h * DK + chunk * 8] = val;
    }
}

// ---------------- in-place LayerNorm ----------------
__global__ __launch_bounds__(256) void ln_inplace(float* __restrict__ y,
                                                  const float* __restrict__ gamma,
                                                  const float* __restrict__ beta) {
    const int row = blockIdx.x;
    float* p = y + (size_t)row * DMODEL;
    const int tid = threadIdx.x;
    float4 v = *(const float4*)(p + tid * 4);
    float s  = v.x + v.y + v.z + v.w;
    float sq = v.x * v.x + v.y * v.y + v.z * v.z + v.w * v.w;
#pragma unroll
    for (int m = 1; m < 64; m <<= 1) {
        s  += __shfl_xor(s, m);
        sq += __shfl_xor(sq, m);
    }
    __shared__ float rs[4], rq[4];
    if ((tid & 63) == 0) { rs[tid >> 6] = s; rq[tid >> 6] = sq; }
    __syncthreads();
    s  = rs[0] + rs[1] + rs[2] + rs[3];
    sq = rq[0] + rq[1] + rq[2] + rq[3];
    const float mean = s * (1.0f / 1024.0f);
    const float var  = sq * (1.0f / 1024.0f) - mean * mean;
    const float inv  = rsqrtf(var + 1e-5f);
    const int c = tid * 4;
    float4 g4 = *(const float4*)(gamma + c);
    float4 b4 = *(const float4*)(beta + c);
    float4 o;
    o.x = (v.x - mean) * inv * g4.x + b4.x;
    o.y = (v.y - mean) * inv * g4.y + b4.y;
    o.z = (v.z - mean) * inv * g4.z + b4.z;
    o.w = (v.w - mean) * inv * g4.w + b4.w;
    *(float4*)(p + c) = o;
}

extern "C" void kernel_launch(void* const* d_in, const int* in_sizes, int n_in,
                              void* d_out, int out_size, void* d_ws, size_t ws_size,
                              hipStream_t stream) {
    const float* x     = (const float*)d_in[0];
    const float* Wq    = (const float*)d_in[1];
    const float* bq    = (const float*)d_in[2];
    const float* Wk    = (const float*)d_in[3];
    const float* bk    = (const float*)d_in[4];
    const float* Wv    = (const float*)d_in[5];
    const float* bv    = (const float*)d_in[6];
    const float* Wo    = (const float*)d_in[7];
    const float* bo    = (const float*)d_in[8];
    const float* gamma = (const float*)d_in[9];
    const float* beta  = (const float*)d_in[10];
    float* out = (float*)d_out;

    u16* x_bf    = (u16*)d_ws;
    u16* Wqkv_bf = x_bf + (size_t)NROWS * DMODEL;
    u16* Wo_bf   = Wqkv_bf + (size_t)3072 * 1024;
    u16* Q_bf    = Wo_bf + (size_t)1024 * 1024;
    u16* K_bf    = Q_bf + (size_t)64 * SEQ * DK;
    u16* Vt_bf   = K_bf + (size_t)64 * SEQ * DK;
    u16* ctx_bf  = x_bf;  // alias: x_bf dead after QKV GEMM

    cvt_all<<<12288, 256, 0, stream>>>(x, Wq, Wk, Wv, Wo,
                                       x_bf, Wqkv_bf, Wqkv_bf + 1048576,
                                       Wqkv_bf + 2097152, Wo_bf);

    gemm_piped<0><<<dim3(64, 24), 512, 0, stream>>>(x_bf, Wqkv_bf,
                                                    bq, bk, bv, Q_bf, K_bf, Vt_bf,
                                                    nullptr, nullptr);
    attn<<<dim3(64, 8), 512, 0, stream>>>(Q_bf, K_bf, Vt_bf, ctx_bf);
    gemm_piped<1><<<dim3(64, 8), 512, 0, stream>>>(ctx_bf, Wo_bf,
                                                   bo, nullptr, nullptr,
                                                   nullptr, nullptr, nullptr,
                                                   x, out);
    ln_inplace<<<8192, 256, 0, stream>>>(out, gamma, beta);
}

// Round 18
// 185.830 us; speedup vs baseline: 1.0054x; 1.0054x over previous
//
#include <hip/hip_runtime.h>

// Fused MHA block: out = LayerNorm(x + MHA(x)).  B=4, S=2048, D=1024, H=16, dk=64.
// bf16 MFMA internal, fp32 I/O.
//
// Round 18: RECOVERY — restore Round 14 verbatim (best verified: 185.8us,
// absmax 0.03125). R17's cooperative gemm_o+LN fusion silently failed under
// graph capture (d_out never written) — cooperative launches are off-limits
// in this harness. R15 (KVBLK=128) and R16 (triple-buffer) were neutral or
// worse; R14 is the converged configuration:
//   - attn: swapped-QK^T 32x32 MFMA, no-max Schraudolph softmax, dot2 l-sum,
//     permlane32_swap P-exchange, gload_lds dbuf, XOR-swizzled LDS (83.5us)
//   - GEMMs: counted-vmcnt 128x128 2-blocks/CU pipeline (vmcnt(4), raw barrier)
//   - cvt_all fused convert; ln_inplace fp32.

#define SEQ 2048
#define DMODEL 1024
#define NH 16
#define DK 64
#define NROWS 8192  // B*S

typedef unsigned short u16;
typedef unsigned int u32;
typedef __bf16 bf16;
typedef bf16 bf16x2 __attribute__((ext_vector_type(2)));
typedef bf16 bf16x8 __attribute__((ext_vector_type(8)));
typedef float f32x4 __attribute__((ext_vector_type(4)));
typedef float f32x16 __attribute__((ext_vector_type(16)));
typedef unsigned u32x2 __attribute__((ext_vector_type(2)));

__device__ inline u16 bfbits(float f) { return __builtin_bit_cast(u16, (bf16)f); }
__device__ inline u32 packbf2(float a, float b) {
    return (u32)bfbits(a) | ((u32)bfbits(b) << 16);
}

// Schraudolph exp2 (validated R8+): full-rate VALU, error cancels in norm.
__device__ inline float sexp2(float s) {
    return __builtin_bit_cast(float, (u32)(int)fmaf(s, 8388608.0f, 1064986823.0f));
}

// async global->LDS, 16B per lane; LDS dest = wave-uniform base + lane*16
__device__ inline void gload16(const u16* g, u16* l) {
    __builtin_amdgcn_global_load_lds(
        (const __attribute__((address_space(1))) u32*)g,
        (__attribute__((address_space(3))) u32*)l, 16, 0, 0);
}

// cross-half exchange (validated rounds 2-16)
__device__ inline void plswap(u32& a, u32& b) {
#if __has_builtin(__builtin_amdgcn_permlane32_swap)
    u32x2 r = __builtin_amdgcn_permlane32_swap(a, b, false, false);
    a = r[0]; b = r[1];
#else
    u32 xa = __shfl_xor(a, 32), xb = __shfl_xor(b, 32);
    int hi = (threadIdx.x & 63) >> 5;
    u32 na = hi ? xb : a;
    u32 nb = hi ? b : xa;
    a = na; b = nb;
#endif
}

// ---------------- fused fp32 -> bf16 convert: x + 4 weights ----------------
__global__ __launch_bounds__(256) void cvt_all(
    const float* __restrict__ x,  const float* __restrict__ w0,
    const float* __restrict__ w1, const float* __restrict__ w2,
    const float* __restrict__ w3,
    u16* __restrict__ xo, u16* __restrict__ o0, u16* __restrict__ o1,
    u16* __restrict__ o2, u16* __restrict__ o3) {
    const int b = blockIdx.x;
    const float* in;
    u16* out;
    int base;
    if (b < 8192) {
        in = x; out = xo; base = b << 10;
    } else {
        const int wsel = (b - 8192) >> 10;
        base = ((b - 8192) & 1023) << 10;
        switch (wsel) {
            case 0: in = w0; out = o0; break;
            case 1: in = w1; out = o1; break;
            case 2: in = w2; out = o2; break;
            default: in = w3; out = o3; break;
        }
    }
    const int i = base + threadIdx.x * 4;
    float4 v = *(const float4*)(in + i);
    ushort4 o;
    o.x = bfbits(v.x); o.y = bfbits(v.y); o.z = bfbits(v.z); o.w = bfbits(v.w);
    *(ushort4*)(out + i) = o;
}

// ---------------- unified counted-vmcnt GEMM (R13) ----------------
template <int EPI>
__global__ __launch_bounds__(512) void gemm_piped(
    const u16* __restrict__ A, const u16* __restrict__ Bm,
    const float* __restrict__ bias0, const float* __restrict__ bias1,
    const float* __restrict__ bias2,
    u16* __restrict__ Qo, u16* __restrict__ Ko, u16* __restrict__ Vo,
    const float* __restrict__ xres, float* __restrict__ yout) {
    __shared__ __align__(16) u16 smem[32768];   // As[2]@0, Bs[2]@16384 (elems)

    const int tid  = threadIdx.x;
    const int lane = tid & 63;
    const int w    = tid >> 6;
    const int wr   = (w >> 1) * 32;
    const int wc   = (w & 1) * 64;
    const int l16  = lane & 15;
    const int lq   = lane >> 4;
    const int m0   = blockIdx.x * 128;
    const int n0   = blockIdx.y * 128;

    f32x4 acc[2][4];
#pragma unroll
    for (int m = 0; m < 2; m++)
#pragma unroll
        for (int n = 0; n < 4; n++) {
            f32x4 z = {0.f, 0.f, 0.f, 0.f};
            acc[m][n] = z;
        }

    const int l8r = lane >> 3;
    const int sch = (lane & 7) ^ l8r;
    const u16* a_g = A  + (size_t)(m0 + w * 8 + l8r) * 1024 + sch * 8;
    const u16* b_g = Bm + (size_t)(n0 + w * 8 + l8r) * 1024 + sch * 8;
    u16* asd = smem + w * 512;
    u16* bsd = smem + 16384 + w * 512;

#define STAGE(kt, c) do {                                              \
        gload16(a_g + (kt) * 64,         asd + (c) * 8192);            \
        gload16(a_g + 65536 + (kt) * 64, asd + (c) * 8192 + 4096);     \
        gload16(b_g + (kt) * 64,         bsd + (c) * 8192);            \
        gload16(b_g + 65536 + (kt) * 64, bsd + (c) * 8192 + 4096);     \
    } while (0)

    STAGE(0, 0);
    STAGE(1, 1);

    for (int kt = 0; kt < 16; kt++) {
        const int cur = kt & 1;
        if (kt < 15) asm volatile("s_waitcnt vmcnt(4)" ::: "memory");
        else         asm volatile("s_waitcnt vmcnt(0)" ::: "memory");
        __builtin_amdgcn_s_barrier();

        const u16* Asl = smem + cur * 8192;
        const u16* Bsl = smem + 16384 + cur * 8192;
#pragma unroll
        for (int kk = 0; kk < 2; kk++) {
            bf16x8 af[2], bfr[4];
#pragma unroll
            for (int m = 0; m < 2; m++)
                af[m] = *(const bf16x8*)&Asl[(wr + m * 16 + l16) * 64 +
                                             (((kk << 2) | lq) ^ (l16 & 7)) * 8];
#pragma unroll
            for (int n = 0; n < 4; n++)
                bfr[n] = *(const bf16x8*)&Bsl[(wc + n * 16 + l16) * 64 +
                                              (((kk << 2) | lq) ^ (l16 & 7)) * 8];
            __builtin_amdgcn_s_setprio(1);
#pragma unroll
            for (int m = 0; m < 2; m++)
#pragma unroll
                for (int n = 0; n < 4; n++)
                    acc[m][n] = __builtin_amdgcn_mfma_f32_16x16x32_bf16(
                        af[m], bfr[n], acc[m][n], 0, 0, 0);
            __builtin_amdgcn_s_setprio(0);
        }
        __builtin_amdgcn_s_barrier();
        if (kt < 14) STAGE(kt + 2, cur);
    }
#undef STAGE

    if (EPI == 0 && n0 >= 2048) {
        const int e0 = n0 - 2048;
#pragma unroll
        for (int m = 0; m < 2; m++)
#pragma unroll
            for (int n = 0; n < 4; n++) {
                const int col = wc + n * 16 + l16;
                const int row = wr + lq * 4 + m * 16;
                const float bias = bias2[e0 + col];
                ushort4 pk;
                pk.x = bfbits(acc[m][n][0] + bias);
                pk.y = bfbits(acc[m][n][1] + bias);
                pk.z = bfbits(acc[m][n][2] + bias);
                pk.w = bfbits(acc[m][n][3] + bias);
                *(ushort4*)&smem[col * 128 + (row ^ ((col & 7) << 3))] = pk;
            }
        __syncthreads();
        const int b = m0 >> 11;
        const int sbase = m0 & 2047;
#pragma unroll
        for (int i = 0; i < 4; i++) {
            const int c = tid + 512 * i;
            const int col = c >> 4;
            const int s0 = (c & 15) * 8;
            uint4 val = *(const uint4*)&smem[col * 128 + (s0 ^ ((col & 7) << 3))];
            const int eg = e0 + col;
            const int bh = b * NH + (eg >> 6);
            *(uint4*)&Vo[((size_t)bh * DK + (eg & 63)) * SEQ + sbase + s0] = val;
        }
        return;
    }

    const int rbase = m0 + wr + lq * 4;
#pragma unroll
    for (int m = 0; m < 2; m++)
#pragma unroll
        for (int n = 0; n < 4; n++) {
            if (EPI == 0) {
                const int which = n0 >> 10;
                const int e = (n0 & 1023) + wc + n * 16 + l16;
                const float bias = (which == 0) ? bias0[e] : bias1[e];
                const int h = e >> 6, d = e & 63;
#pragma unroll
                for (int r = 0; r < 4; r++) {
                    const int row = rbase + m * 16 + r;
                    float v = acc[m][n][r] + bias;
                    if (which == 0) v *= 0.18033688011112042f;
                    const int b = row >> 11, s = row & 2047;
                    const int bh = b * NH + h;
                    if (which == 0)
                        Qo[((size_t)bh * SEQ + s) * DK + d] = bfbits(v);
                    else
                        Ko[((size_t)bh * SEQ + s) * DK + d] = bfbits(v);
                }
            } else {
                const int col = n0 + wc + n * 16 + l16;
#pragma unroll
                for (int r = 0; r < 4; r++) {
                    const int row = rbase + m * 16 + r;
                    float v = acc[m][n][r] + bias0[col] + xres[(size_t)row * DMODEL + col];
                    yout[(size_t)row * DMODEL + col] = v;
                }
            }
        }
}

// ---------------- flash attention (R14: swapped-QK^T, no-max softmax, dot2 l-sum) ----------------
__global__ __launch_bounds__(512) void attn(const u16* __restrict__ Qb,
                                            const u16* __restrict__ Kb,
                                            const u16* __restrict__ Vtb,
                                            u16* __restrict__ ctx) {
    __shared__ __align__(16) u16 smem[16384];

    const int tid  = threadIdx.x;
    const int lane = tid & 63;
    const int w    = tid >> 6;
    const int q    = lane & 31;
    const int hi   = lane >> 5;
    const int bh   = blockIdx.x;
    const int q0   = blockIdx.y * 256 + w * 32;

    const u16* qp = Qb + ((size_t)bh * SEQ + q0 + q) * DK + hi * 8;
    bf16x8 qf0 = *(const bf16x8*)(qp);
    bf16x8 qf1 = *(const bf16x8*)(qp + 16);
    bf16x8 qf2 = *(const bf16x8*)(qp + 32);
    bf16x8 qf3 = *(const bf16x8*)(qp + 48);

    const int l8r = lane >> 3;
    const int sch = (lane & 7) ^ l8r;
    const u16* kg = Kb  + ((size_t)bh * SEQ + w * 8 + l8r) * 64 + sch * 8;
    const u16* vg = Vtb + ((size_t)bh * DK  + w * 8 + l8r) * SEQ + sch * 8;
    u16* kl = smem + w * 512;
    u16* vl = smem + 8192 + w * 512;

    f32x16 oacc0, oacc1;
#pragma unroll
    for (int r = 0; r < 16; r++) { oacc0[r] = 0.f; oacc1[r] = 0.f; }
    f32x16 fzero;
#pragma unroll
    for (int r = 0; r < 16; r++) fzero[r] = 0.f;
    float la = 0.f, lb = 0.f;

#if __has_builtin(__builtin_amdgcn_fdot2_f32_bf16)
    bf16x2 ones2;
    ones2[0] = (bf16)1.0f; ones2[1] = (bf16)1.0f;
#endif

    gload16(kg, kl);
    gload16(vg, vl);
    __syncthreads();

    for (int t = 0; t < SEQ / 64; t++) {
        if (t < SEQ / 64 - 1) {
            gload16(kg + (size_t)(t + 1) * 4096, kl + ((t + 1) & 1) * 4096);
            gload16(vg + (size_t)(t + 1) * 64,  vl + ((t + 1) & 1) * 4096);
        }
        const u16* Kl = smem + (t & 1) * 4096;
        const u16* Vl = smem + 8192 + (t & 1) * 4096;

        f32x16 sacc0, sacc1;
        {
            bf16x8 k00 = *(const bf16x8*)&Kl[(q)      * 64 + ((0 | hi) ^ (q & 7)) * 8];
            bf16x8 k01 = *(const bf16x8*)&Kl[(q)      * 64 + ((2 | hi) ^ (q & 7)) * 8];
            bf16x8 k02 = *(const bf16x8*)&Kl[(q)      * 64 + ((4 | hi) ^ (q & 7)) * 8];
            bf16x8 k03 = *(const bf16x8*)&Kl[(q)      * 64 + ((6 | hi) ^ (q & 7)) * 8];
            bf16x8 k10 = *(const bf16x8*)&Kl[(q + 32) * 64 + ((0 | hi) ^ (q & 7)) * 8];
            bf16x8 k11 = *(const bf16x8*)&Kl[(q + 32) * 64 + ((2 | hi) ^ (q & 7)) * 8];
            bf16x8 k12 = *(const bf16x8*)&Kl[(q + 32) * 64 + ((4 | hi) ^ (q & 7)) * 8];
            bf16x8 k13 = *(const bf16x8*)&Kl[(q + 32) * 64 + ((6 | hi) ^ (q & 7)) * 8];
            __builtin_amdgcn_s_setprio(1);
            sacc0 = __builtin_amdgcn_mfma_f32_32x32x16_bf16(k00, qf0, fzero, 0, 0, 0);
            sacc1 = __builtin_amdgcn_mfma_f32_32x32x16_bf16(k10, qf0, fzero, 0, 0, 0);
            sacc0 = __builtin_amdgcn_mfma_f32_32x32x16_bf16(k01, qf1, sacc0, 0, 0, 0);
            sacc1 = __builtin_amdgcn_mfma_f32_32x32x16_bf16(k11, qf1, sacc1, 0, 0, 0);
            sacc0 = __builtin_amdgcn_mfma_f32_32x32x16_bf16(k02, qf2, sacc0, 0, 0, 0);
            sacc1 = __builtin_amdgcn_mfma_f32_32x32x16_bf16(k12, qf2, sacc1, 0, 0, 0);
            sacc0 = __builtin_amdgcn_mfma_f32_32x32x16_bf16(k03, qf3, sacc0, 0, 0, 0);
            sacc1 = __builtin_amdgcn_mfma_f32_32x32x16_bf16(k13, qf3, sacc1, 0, 0, 0);
            __builtin_amdgcn_s_setprio(0);
        }

#pragma unroll
        for (int r = 0; r < 16; r++) sacc0[r] = sexp2(sacc0[r]);
#pragma unroll
        for (int r = 0; r < 16; r++) sacc1[r] = sexp2(sacc1[r]);

        u32 wa[8], wb[8];
#pragma unroll
        for (int i = 0; i < 8; i++) wa[i] = packbf2(sacc0[2 * i], sacc0[2 * i + 1]);
#pragma unroll
        for (int i = 0; i < 8; i++) wb[i] = packbf2(sacc1[2 * i], sacc1[2 * i + 1]);

#if __has_builtin(__builtin_amdgcn_fdot2_f32_bf16)
#pragma unroll
        for (int i = 0; i < 8; i++)
            la = __builtin_amdgcn_fdot2_f32_bf16(
                __builtin_bit_cast(bf16x2, wa[i]), ones2, la, false);
#pragma unroll
        for (int i = 0; i < 8; i++)
            lb = __builtin_amdgcn_fdot2_f32_bf16(
                __builtin_bit_cast(bf16x2, wb[i]), ones2, lb, false);
#else
        {
            float s0 = ((sacc0[0] + sacc0[1]) + (sacc0[2] + sacc0[3])) +
                       ((sacc0[4] + sacc0[5]) + (sacc0[6] + sacc0[7]));
            float s1 = ((sacc0[8] + sacc0[9]) + (sacc0[10] + sacc0[11])) +
                       ((sacc0[12] + sacc0[13]) + (sacc0[14] + sacc0[15]));
            float s2 = ((sacc1[0] + sacc1[1]) + (sacc1[2] + sacc1[3])) +
                       ((sacc1[4] + sacc1[5]) + (sacc1[6] + sacc1[7]));
            float s3 = ((sacc1[8] + sacc1[9]) + (sacc1[10] + sacc1[11])) +
                       ((sacc1[12] + sacc1[13]) + (sacc1[14] + sacc1[15]));
            la += (s0 + s1);
            lb += (s2 + s3);
        }
#endif

        plswap(wa[0], wa[2]); plswap(wa[1], wa[3]);
        plswap(wa[4], wa[6]); plswap(wa[5], wa[7]);
        plswap(wb[0], wb[2]); plswap(wb[1], wb[3]);
        plswap(wb[4], wb[6]); plswap(wb[5], wb[7]);
        union { u32 u[4]; bf16x8 v; } pf0, pf1, pf2, pf3;
        pf0.u[0] = wa[0]; pf0.u[1] = wa[1]; pf0.u[2] = wa[2]; pf0.u[3] = wa[3];
        pf1.u[0] = wa[4]; pf1.u[1] = wa[5]; pf1.u[2] = wa[6]; pf1.u[3] = wa[7];
        pf2.u[0] = wb[0]; pf2.u[1] = wb[1]; pf2.u[2] = wb[2]; pf2.u[3] = wb[3];
        pf3.u[0] = wb[4]; pf3.u[1] = wb[5]; pf3.u[2] = wb[6]; pf3.u[3] = wb[7];

        {
            bf16x8 v00 = *(const bf16x8*)&Vl[(q)      * 64 + ((0 | hi) ^ (q & 7)) * 8];
            bf16x8 v01 = *(const bf16x8*)&Vl[(q)      * 64 + ((2 | hi) ^ (q & 7)) * 8];
            bf16x8 v02 = *(const bf16x8*)&Vl[(q)      * 64 + ((4 | hi) ^ (q & 7)) * 8];
            bf16x8 v03 = *(const bf16x8*)&Vl[(q)      * 64 + ((6 | hi) ^ (q & 7)) * 8];
            bf16x8 v10 = *(const bf16x8*)&Vl[(q + 32) * 64 + ((0 | hi) ^ (q & 7)) * 8];
            bf16x8 v11 = *(const bf16x8*)&Vl[(q + 32) * 64 + ((2 | hi) ^ (q & 7)) * 8];
            bf16x8 v12 = *(const bf16x8*)&Vl[(q + 32) * 64 + ((4 | hi) ^ (q & 7)) * 8];
            bf16x8 v13 = *(const bf16x8*)&Vl[(q + 32) * 64 + ((6 | hi) ^ (q & 7)) * 8];
            __builtin_amdgcn_s_setprio(1);
            oacc0 = __builtin_amdgcn_mfma_f32_32x32x16_bf16(v00, pf0.v, oacc0, 0, 0, 0);
            oacc1 = __builtin_amdgcn_mfma_f32_32x32x16_bf16(v10, pf0.v, oacc1, 0, 0, 0);
            oacc0 = __builtin_amdgcn_mfma_f32_32x32x16_bf16(v01, pf1.v, oacc0, 0, 0, 0);
            oacc1 = __builtin_amdgcn_mfma_f32_32x32x16_bf16(v11, pf1.v, oacc1, 0, 0, 0);
            oacc0 = __builtin_amdgcn_mfma_f32_32x32x16_bf16(v02, pf2.v, oacc0, 0, 0, 0);
            oacc1 = __builtin_amdgcn_mfma_f32_32x32x16_bf16(v12, pf2.v, oacc1, 0, 0, 0);
            oacc0 = __builtin_amdgcn_mfma_f32_32x32x16_bf16(v03, pf3.v, oacc0, 0, 0, 0);
            oacc1 = __builtin_amdgcn_mfma_f32_32x32x16_bf16(v13, pf3.v, oacc1, 0, 0, 0);
            __builtin_amdgcn_s_setprio(0);
        }

        __syncthreads();
    }

    float l_ = la + lb;
    const float lfull = l_ + __shfl_xor(l_, 32);
    const float invl = 1.f / lfull;
    const int wbase = w * 2048;
#pragma unroll
    for (int r = 0; r < 16; r++) {
        const int dk0 = (r & 3) + 8 * (r >> 2) + 4 * hi;
        const int dk1 = 32 + dk0;
        smem[wbase + q * 64 + (((dk0 >> 3) ^ (q & 7)) << 3) + (dk0 & 7)] = bfbits(oacc0[r] * invl);
        smem[wbase + q * 64 + (((dk1 >> 3) ^ (q & 7)) << 3) + (dk1 & 7)] = bfbits(oacc1[r] * invl);
    }
    __syncthreads();
    const int b = bh >> 4, h = bh & 15;
    const int r4 = lane >> 1;
    const int cc = (lane & 1) * 4;
#pragma unroll
    for (int c = 0; c < 4; c++) {
        const int chunk = cc + c;
        uint4 val = *(const uint4*)&smem[wbase + r4 * 64 + ((chunk ^ (r4 & 7)) << 3)];
        *(uint4*)&ctx[((size_t)(b * SEQ + q0 + r4)) * DMODEL + h * DK + chunk * 8] = val;
    }
}

// ---------------- in-place LayerNorm ----------------
__global__ __launch_bounds__(256) void ln_inplace(float* __restrict__ y,
                                                  const float* __restrict__ gamma,
                                                  const float* __restrict__ beta) {
    const int row = blockIdx.x;
    float* p = y + (size_t)row * DMODEL;
    const int tid = threadIdx.x;
    float4 v = *(const float4*)(p + tid * 4);
    float s  = v.x + v.y + v.z + v.w;
    float sq = v.x * v.x + v.y * v.y + v.z * v.z + v.w * v.w;
#pragma unroll
    for (int m = 1; m < 64; m <<= 1) {
        s  += __shfl_xor(s, m);
        sq += __shfl_xor(sq, m);
    }
    __shared__ float rs[4], rq[4];
    if ((tid & 63) == 0) { rs[tid >> 6] = s; rq[tid >> 6] = sq; }
    __syncthreads();
    s  = rs[0] + rs[1] + rs[2] + rs[3];
    sq = rq[0] + rq[1] + rq[2] + rq[3];
    const float mean = s * (1.0f / 1024.0f);
    const float var  = sq * (1.0f / 1024.0f) - mean * mean;
    const float inv  = rsqrtf(var + 1e-5f);
    const int c = tid * 4;
    float4 g4 = *(const float4*)(gamma + c);
    float4 b4 = *(const float4*)(beta + c);
    float4 o;
    o.x = (v.x - mean) * inv * g4.x + b4.x;
    o.y = (v.y - mean) * inv * g4.y + b4.y;
    o.z = (v.z - mean) * inv * g4.z + b4.z;
    o.w = (v.w - mean) * inv * g4.w + b4.w;
    *(float4*)(p + c) = o;
}

extern "C" void kernel_launch(void* const* d_in, const int* in_sizes, int n_in,
                              void* d_out, int out_size, void* d_ws, size_t ws_size,
                              hipStream_t stream) {
    const float* x     = (const float*)d_in[0];
    const float* Wq    = (const float*)d_in[1];
    const float* bq    = (const float*)d_in[2];
    const float* Wk    = (const float*)d_in[3];
    const float* bk    = (const float*)d_in[4];
    const float* Wv    = (const float*)d_in[5];
    const float* bv    = (const float*)d_in[6];
    const float* Wo    = (const float*)d_in[7];
    const float* bo    = (const float*)d_in[8];
    const float* gamma = (const float*)d_in[9];
    const float* beta  = (const float*)d_in[10];
    float* out = (float*)d_out;

    u16* x_bf    = (u16*)d_ws;
    u16* Wqkv_bf = x_bf + (size_t)NROWS * DMODEL;
    u16* Wo_bf   = Wqkv_bf + (size_t)3072 * 1024;
    u16* Q_bf    = Wo_bf + (size_t)1024 * 1024;
    u16* K_bf    = Q_bf + (size_t)64 * SEQ * DK;
    u16* Vt_bf   = K_bf + (size_t)64 * SEQ * DK;
    u16* ctx_bf  = x_bf;  // alias: x_bf dead after QKV GEMM

    cvt_all<<<12288, 256, 0, stream>>>(x, Wq, Wk, Wv, Wo,
                                       x_bf, Wqkv_bf, Wqkv_bf + 1048576,
                                       Wqkv_bf + 2097152, Wo_bf);

    gemm_piped<0><<<dim3(64, 24), 512, 0, stream>>>(x_bf, Wqkv_bf,
                                                    bq, bk, bv, Q_bf, K_bf, Vt_bf,
                                                    nullptr, nullptr);
    attn<<<dim3(64, 8), 512, 0, stream>>>(Q_bf, K_bf, Vt_bf, ctx_bf);
    gemm_piped<1><<<dim3(64, 8), 512, 0, stream>>>(ctx_bf, Wo_bf,
                                                   bo, nullptr, nullptr,
                                                   nullptr, nullptr, nullptr,
                                                   x, out);
    ln_inplace<<<8192, 256, 0, stream>>>(out, gamma, beta);
}